// Round 2
// 717.345 us; speedup vs baseline: 1.0952x; 1.0952x over previous
//
#include <hip/hip_runtime.h>

// Problem constants:
//   BATCH = 1048576, EMB_DIM = 146 (= 128 emb + 18 genre)
// Output row = 146 f32 = 584 B = 73 float2. Two rows = 1168 B = 73 float4,
// and TOTAL float2 count is even, so we index the OUTPUT in float4 units:
//   each thread builds one 16 B output chunk from two float2 gathers.
//
// Key changes vs the 395-us-dispatch version:
//  1. __builtin_nontemporal_store on the 612 MB output stream so it stops
//     evicting the 58 MB gather tables from the 4 MiB/XCD L2s.
//     (Uses a clang ext_vector_type float4 — HIP's float4 class is rejected
//      by the builtin.)
//  2. float4 (16 B) coalesced stores: half the threads/stores/idx loads/divides.
//  3. Each thread handles TWO independent output float4s (g and g+HALF) ->
//     two independent idx->table dependency chains in flight per thread.

#define BATCH     1048576u
#define ROW_F2    73u                       // float2 per output row
#define EMB_F2    64u                       // float2 per embedding row (128 f32)
#define GENRE_F2  9u                        // float2 per genre row (18 f32)
#define TOTAL_F4  (BATCH * ROW_F2 / 2u)     // 38,273,024 float4 of output
#define HALF_F4   (TOTAL_F4 / 2u)           // 19,136,512 (= 74752 * 256, exact)

typedef float f32x4 __attribute__((ext_vector_type(4)));

__device__ __forceinline__ float2 load_src(const float2* __restrict__ emb,
                                           const float2* __restrict__ genre,
                                           unsigned item, unsigned c2)
{
    // c2 in [0,73): 0..63 -> embedding row, 64..72 -> genre row
    if (c2 < EMB_F2)
        return emb[item * EMB_F2 + c2];
    else
        return genre[item * GENRE_F2 + (c2 - EMB_F2)];
}

__device__ __forceinline__ f32x4 gather16(const int* __restrict__ idx,
                                          const float2* __restrict__ emb,
                                          const float2* __restrict__ genre,
                                          unsigned g)
{
    unsigned e   = 2u * g;                  // float2 index, < 76,546,048 < 2^31
    unsigned row = e / ROW_F2;              // magic-mul division
    unsigned c2  = e - row * ROW_F2;

    unsigned item = (unsigned)idx[row];

    float2 a = load_src(emb, genre, item, c2);
    float2 b;
    if (c2 < ROW_F2 - 1u) {
        b = load_src(emb, genre, item, c2 + 1u);
    } else {
        // e is even and row stride (73) is odd, so c2==72 only occurs at odd
        // row parity positions; when it does, the next float2 belongs to the
        // NEXT row, and row+1 < BATCH there (last element of last row is
        // c2==72 at row==BATCH-1 only if total count were odd — it is even,
        // and the final float4 ends exactly at the buffer end with c2==71/72
        // pair inside the row). idx[row+1] is in bounds for every g < HALF_F4
        // and g+HALF_F4 < TOTAL_F4 except the very last float4, which has
        // c2 == 71 (even), so the else-branch never reads idx[BATCH].
        b = load_src(emb, genre, (unsigned)idx[row + 1u], 0u);
    }
    f32x4 v;
    v.x = a.x; v.y = a.y; v.z = b.x; v.w = b.y;
    return v;
}

__global__ __launch_bounds__(256) void item_emb_gather_concat(
    const int*    __restrict__ idx,     // [BATCH] int32
    const float2* __restrict__ emb,     // [NUM_ITEMS][64] float2
    const float2* __restrict__ genre,   // [NUM_ITEMS][9]  float2
    f32x4*        __restrict__ out)     // [BATCH*73/2] float4
{
    unsigned g = blockIdx.x * 256u + threadIdx.x;   // < HALF_F4, exact grid

    // Two independent gather chains (separate coalesced half-streams).
    f32x4 v0 = gather16(idx, emb, genre, g);
    f32x4 v1 = gather16(idx, emb, genre, g + HALF_F4);

    // Output is write-once: non-temporal so it doesn't thrash L2.
    __builtin_nontemporal_store(v0, &out[g]);
    __builtin_nontemporal_store(v1, &out[g + HALF_F4]);
}

extern "C" void kernel_launch(void* const* d_in, const int* in_sizes, int n_in,
                              void* d_out, int out_size, void* d_ws, size_t ws_size,
                              hipStream_t stream) {
    const int*    idx   = (const int*)d_in[0];
    const float2* emb   = (const float2*)d_in[1];
    const float2* genre = (const float2*)d_in[2];
    f32x4*        out   = (f32x4*)d_out;

    const unsigned block = 256;
    const unsigned grid  = HALF_F4 / block;   // 74,752 blocks, no remainder
    item_emb_gather_concat<<<grid, block, 0, stream>>>(idx, emb, genre, out);
}

// Round 3
// 698.682 us; speedup vs baseline: 1.1244x; 1.0267x over previous
//
#include <hip/hip_runtime.h>

// BATCH = 1048576, row = 146 f32 = 584 B = 73 float2; emb part 128 f32, genre 18 f32.
// Output indexed as float4 (16 B): TOTAL_F4 = BATCH*73/2 = 38,273,024.
// Each thread builds FOUR output float4s, one from each quarter-stream:
// 4 fully independent, fully BRANCHLESS gather chains -> ~12 loads in flight
// per thread, no exec-mask divergence, no intermediate s_waitcnt.
//
// vs Round-2 version (~330 us dispatch): the divergent emb/genre and
// row-boundary branches serialized the loads; here the emb-vs-genre and
// same-row-vs-next-row choices are v_cndmask address selects.

#define BATCH     1048576u
#define ROW_F2    73u
#define EMB_F2    64u
#define GENRE_F2  9u
#define TOTAL_F4  (BATCH * ROW_F2 / 2u)     // 38,273,024
#define Q_F4      (TOTAL_F4 / 4u)           // 9,568,256 = 37,376 * 256 exact

typedef float f32x4 __attribute__((ext_vector_type(4)));

__device__ __forceinline__ f32x4 gather16(const int*    __restrict__ idx,
                                          const float2* __restrict__ emb,
                                          const float2* __restrict__ genre,
                                          unsigned g)
{
    unsigned e   = 2u * g;                  // float2 index, < 2^31
    unsigned row = e / ROW_F2;              // magic-mul division
    unsigned c2  = e - row * ROW_F2;

    // second float2 of this 16B chunk: either c2+1 in same row, or col 0 of
    // the next row (c2==72 case; never OOB — last chunk ends at c2==71/72
    // inside the last row, and c2==72 implies row+1 < BATCH).
    unsigned bump = (c2 == ROW_F2 - 1u) ? 1u : 0u;
    unsigned row1 = row + bump;
    unsigned c2b  = bump ? 0u : (c2 + 1u);

    unsigned item0 = (unsigned)idx[row];
    unsigned item1 = (unsigned)idx[row1];   // usually same cacheline as idx[row]

    // Branchless address select: emb row (64 float2) vs genre row (9 float2).
    const float2* p0 = (c2 < EMB_F2)
        ? emb   + ((size_t)item0 * EMB_F2   + c2)
        : genre + ((size_t)item0 * GENRE_F2 + (c2 - EMB_F2));
    const float2* p1 = (c2b < EMB_F2)
        ? emb   + ((size_t)item1 * EMB_F2   + c2b)
        : genre + ((size_t)item1 * GENRE_F2 + (c2b - EMB_F2));

    float2 a = *p0;
    float2 b = *p1;
    f32x4 v; v.x = a.x; v.y = a.y; v.z = b.x; v.w = b.y;
    return v;
}

__global__ __launch_bounds__(256) void item_emb_gather_concat(
    const int*    __restrict__ idx,     // [BATCH] int32
    const float2* __restrict__ emb,     // [NUM_ITEMS][64] float2
    const float2* __restrict__ genre,   // [NUM_ITEMS][9]  float2
    f32x4*        __restrict__ out)     // [TOTAL_F4] float4
{
    unsigned g = blockIdx.x * 256u + threadIdx.x;   // < Q_F4, exact grid

    // Four independent branchless gather chains (quarter-streams).
    f32x4 v0 = gather16(idx, emb, genre, g);
    f32x4 v1 = gather16(idx, emb, genre, g +      Q_F4);
    f32x4 v2 = gather16(idx, emb, genre, g + 2u * Q_F4);
    f32x4 v3 = gather16(idx, emb, genre, g + 3u * Q_F4);

    // Output is write-once: non-temporal keeps the 58 MB tables in L2.
    __builtin_nontemporal_store(v0, &out[g]);
    __builtin_nontemporal_store(v1, &out[g +      Q_F4]);
    __builtin_nontemporal_store(v2, &out[g + 2u * Q_F4]);
    __builtin_nontemporal_store(v3, &out[g + 3u * Q_F4]);
}

extern "C" void kernel_launch(void* const* d_in, const int* in_sizes, int n_in,
                              void* d_out, int out_size, void* d_ws, size_t ws_size,
                              hipStream_t stream) {
    const int*    idx   = (const int*)d_in[0];
    const float2* emb   = (const float2*)d_in[1];
    const float2* genre = (const float2*)d_in[2];
    f32x4*        out   = (f32x4*)d_out;

    const unsigned block = 256;
    const unsigned grid  = Q_F4 / block;    // 37,376 blocks, no remainder
    item_emb_gather_concat<<<grid, block, 0, stream>>>(idx, emb, genre, out);
}